// Round 10
// baseline (97.167 us; speedup 1.0000x reference)
//
#include <hip/hip_runtime.h>

// MoE block: B=128,K=32 -> N=4096 tokens, D=1024, H=256, E=32, top-1 routing.
// out[tok] = relu(relu(x[tok] @ W1[e] + b1[e]) @ W2[e] + b2[e]), e = argmax(x@rw.T+rb)
// 2 kernels (+1 tiny memset): K1 router + tail-block scan/scatter (R7-proven fence
// pattern); K2 persistent GEMM (256 co-resident blocks): per-XCD-class L1 tile list,
// then L2 tile list gated per-expert by release/acquire ready counters -> W1 and W2
// streaming overlap across experts instead of a serial phase boundary.

#define N_TOK 4096
#define DDIM  1024
#define HDIM  256
#define NEXP  32
#define TPX   136          // max 32-token tiles per XCD class (<=132 worst case)

typedef __attribute__((ext_vector_type(8))) short bf16x8;   // 8 bf16 in 4 VGPRs
typedef __attribute__((ext_vector_type(4))) float f32x4;

__device__ __forceinline__ unsigned short f2bf(float f) {   // RNE f32->bf16
  union { float f; unsigned u; } v; v.f = f;
  unsigned r = v.u + 0x7FFFu + ((v.u >> 16) & 1u);
  return (unsigned short)(r >> 16);
}
__device__ __forceinline__ float bf2f(unsigned short h) {
  union { unsigned u; float f; } v; v.u = ((unsigned)h) << 16;
  return v.f;
}
// LDS tile addressing: row-major stride 72 shorts, kk bits 3-5 XORed with (row>>3)&7.
// b128 frag reads and b64 staging writes at the wave64 bank floor (derived R5/R7).
__device__ __forceinline__ int swz(int row, int kk) {
  return row * 72 + (kk ^ (((row >> 3) & 7) << 3));
}

// ---------------- K1: router + tail-block scan (R7 fence pattern, isolated) ----------
// Router: 8 waves per 16-token tile, wave w owns K window [w*128,+128); fp32-accurate
// logits via 4-term bf16 hi/lo split MFMA. Last block (threadfence + done counter)
// builds histogram, XCD-pinned 32-token tile slots, nt[e] table, and order array.
__global__ __launch_bounds__(512) void router_scan_kernel(
    const float* __restrict__ x, const float* __restrict__ rw,
    const float* __restrict__ rb, int* __restrict__ routed,
    int* __restrict__ meta, int* __restrict__ order, int* __restrict__ done) {
  __shared__ float red[8][64][8];
  __shared__ int scnt[NEXP];
  __shared__ int scur[NEXP];
  __shared__ int lastflag;
  int b = blockIdx.x;
  int t = threadIdx.x, w = t >> 6, l = t & 63;
  int m = l & 15, kb = l >> 4;
  int tok = b * 16 + m;
  int kbase = w * 128;
  bf16x8 wh[2][4], wl[2][4];              // rw rows m, m+16; this thread's k-window
#pragma unroll
  for (int h = 0; h < 2; h++) {
    const float* wp = rw + (size_t)(m + h * 16) * DDIM + kbase + kb * 8;
#pragma unroll
    for (int q = 0; q < 4; q++) {
      float4 f0 = *(const float4*)(wp + q * 32);
      float4 f1 = *(const float4*)(wp + q * 32 + 4);
      float fv[8] = {f0.x, f0.y, f0.z, f0.w, f1.x, f1.y, f1.z, f1.w};
      bf16x8 hi, lo;
#pragma unroll
      for (int i = 0; i < 8; i++) {
        unsigned short hh = f2bf(fv[i]);
        hi[i] = (short)hh;
        lo[i] = (short)f2bf(fv[i] - bf2f(hh));
      }
      wh[h][q] = hi; wl[h][q] = lo;
    }
  }
  const float* xrow = x + (size_t)tok * DDIM + kbase + kb * 8;
  f32x4 acc0 = {0.f,0.f,0.f,0.f}, acc1 = {0.f,0.f,0.f,0.f};
#pragma unroll
  for (int q = 0; q < 4; q++) {
    float4 xa = *(const float4*)(xrow + q * 32);
    float4 xc = *(const float4*)(xrow + q * 32 + 4);
    float xv[8] = {xa.x, xa.y, xa.z, xa.w, xc.x, xc.y, xc.z, xc.w};
    bf16x8 xhi, xlo;
#pragma unroll
    for (int i = 0; i < 8; i++) {
      unsigned short hh = f2bf(xv[i]);
      xhi[i] = (short)hh;
      xlo[i] = (short)f2bf(xv[i] - bf2f(hh));
    }
    acc0 = __builtin_amdgcn_mfma_f32_16x16x32_bf16(xhi, wh[0][q], acc0, 0, 0, 0);
    acc0 = __builtin_amdgcn_mfma_f32_16x16x32_bf16(xlo, wh[0][q], acc0, 0, 0, 0);
    acc0 = __builtin_amdgcn_mfma_f32_16x16x32_bf16(xhi, wl[0][q], acc0, 0, 0, 0);
    acc0 = __builtin_amdgcn_mfma_f32_16x16x32_bf16(xlo, wl[0][q], acc0, 0, 0, 0);
    acc1 = __builtin_amdgcn_mfma_f32_16x16x32_bf16(xhi, wh[1][q], acc1, 0, 0, 0);
    acc1 = __builtin_amdgcn_mfma_f32_16x16x32_bf16(xlo, wh[1][q], acc1, 0, 0, 0);
    acc1 = __builtin_amdgcn_mfma_f32_16x16x32_bf16(xhi, wl[1][q], acc1, 0, 0, 0);
    acc1 = __builtin_amdgcn_mfma_f32_16x16x32_bf16(xlo, wl[1][q], acc1, 0, 0, 0);
  }
  *(f32x4*)&red[w][l][0] = acc0;
  *(f32x4*)&red[w][l][4] = acc1;
  __syncthreads();
  if (w == 0) {
    f32x4 s0 = {0.f,0.f,0.f,0.f}, s1 = {0.f,0.f,0.f,0.f};
#pragma unroll
    for (int ww = 0; ww < 8; ww++) {
      s0 += *(const f32x4*)&red[ww][l][0];
      s1 += *(const f32x4*)&red[ww][l][4];
    }
    float rb0 = rb[m], rb1 = rb[16 + m];
#pragma unroll
    for (int r = 0; r < 4; r++) {       // token row = kb*4+r
      float v0 = s0[r] + rb0;
      float v1 = s1[r] + rb1;
      float val = v0; int idx = m;
      if (v1 > v0) { val = v1; idx = 16 + m; }   // ties -> smaller e (np.argmax)
#pragma unroll
      for (int s = 1; s < 16; s <<= 1) {
        float ov = __shfl_xor(val, s);
        int oi = __shfl_xor(idx, s);
        if (ov > val || (ov == val && oi < idx)) { val = ov; idx = oi; }
      }
      if (m == 0) routed[b * 16 + kb * 4 + r] = idx;
    }
  }
  // ---- tail-block scan: last block to finish builds meta/order (R7 pattern) ----
  __syncthreads();
  if (t == 0) {
    __threadfence();                    // release: my routed writes visible
    int v = atomicAdd(done, 1);         // device-scope
    lastflag = (v == 255);
    if (lastflag) __threadfence();      // acquire: everyone's routed visible
  }
  __syncthreads();
  if (!lastflag) return;
  if (t < NEXP) scnt[t] = 0;
  __syncthreads();
  for (int n = t; n < N_TOK; n += 512) atomicAdd(&scnt[routed[n]], 1);
  __syncthreads();
  if (t < NEXP) {                       // lanes 0..31 of wave 0
    int c = scnt[t];
    int nt = (c + 31) >> 5;             // 32-token tiles
    meta[1096 + t] = nt;                // nt[e] table for K2's ready counters
    int ic = c;
#pragma unroll
    for (int s = 1; s < NEXP; s <<= 1) {
      int pc = __shfl_up(ic, s);
      if (t >= s) ic += pc;
    }
    int off = ic - c;
    scur[t] = off;
    int cls = t & 7, pos = t >> 3;      // XCD class, rank-in-class position
    int rank = 0;
#pragma unroll
    for (int j = 0; j < 4; j++) {
      int v = __shfl(nt, cls + j * 8);
      if (pos > j) rank += v;
    }
    for (int s2 = 0; s2 < nt; s2++) {
      int nr = c - s2 * 32; if (nr > 32) nr = 32;
      meta[8 + cls + 8 * (rank + s2)] = (t << 24) | (nr << 16) | (off + s2 * 32);
    }
    if (pos == 3) meta[cls] = rank + nt;  // per-class tile count
  }
  __syncthreads();
  for (int n = t; n < N_TOK; n += 512) {
    int e = routed[n];
    int p = atomicAdd(&scur[e], 1);     // intra-expert order arbitrary: out invariant
    order[p] = n;
  }
}

// ---------------- GEMM tile body (R9 K-loop: depth-2 reg prefetch, swizzled LDS) -----
template <int KDIM, int NTOT, bool A_FP32, bool OUT_BF16>
__device__ __forceinline__ void gemm_tile(
    const void* __restrict__ a_src, const float* __restrict__ wsrc,
    const float* __restrict__ bias, const int* __restrict__ order,
    void* __restrict__ outp, int e, int nrow, int ts, int c0,
    unsigned short AT[2][32 * 72], unsigned short BT[2][128 * 72]) {
  constexpr int NCH = KDIM / 64;
  int t = threadIdx.x, w = t >> 6, l = t & 63, m = l & 15, kb = l >> 4;
  int atr = t >> 4, ak4 = (t & 15) * 4;
  int bcn = t & 127, bkg = t >> 7;
  int atok = order[ts + (atr < nrow ? atr : nrow - 1)];   // clamp: masked at store
  const float* aF = (const float*)a_src + (size_t)atok * KDIM + ak4;
  const unsigned short* aH = (const unsigned short*)a_src + (size_t)atok * KDIM + ak4;
  const float* bS = wsrc + (size_t)e * KDIM * NTOT + (size_t)(bkg * 16) * NTOT + c0 + bcn;

  float4 nAf[2]; ushort4 nAh[2];
  float nB[2][16];                            // all indices compile-time (full unroll)
  auto LOADC = [&](int c, int rbuf) {
    if constexpr (A_FP32) nAf[rbuf] = *(const float4*)(aF + c * 64);
    else                  nAh[rbuf] = *(const ushort4*)(aH + c * 64);
#pragma unroll
    for (int j = 0; j < 16; j++)
      nB[rbuf][j] = bS[(size_t)(c * 64 + j) * NTOT];
  };

  f32x4 acc0 = {0.f,0.f,0.f,0.f}, acc1 = {0.f,0.f,0.f,0.f};
  LOADC(0, 0);
  LOADC(1, 1);
#pragma unroll
  for (int c = 0; c < NCH; c++) {
    const int p = c & 1;
    ushort4 av;
    if constexpr (A_FP32) {
      av.x = f2bf(nAf[p].x); av.y = f2bf(nAf[p].y);
      av.z = f2bf(nAf[p].z); av.w = f2bf(nAf[p].w);
    } else av = nAh[p];
    *(ushort4*)&AT[p][swz(atr, ak4)] = av;    // b64: bank floor
#pragma unroll
    for (int j = 0; j < 4; j++) {             // B writes b64: bank floor
      ushort4 pv;
      pv.x = f2bf(nB[p][4*j]);   pv.y = f2bf(nB[p][4*j+1]);
      pv.z = f2bf(nB[p][4*j+2]); pv.w = f2bf(nB[p][4*j+3]);
      *(ushort4*)&BT[p][swz(bcn, bkg * 16 + 4 * j)] = pv;
    }
    if (c + 2 < NCH) LOADC(c + 2, p);         // WAR-safe: ds_writes read regs at issue
    asm volatile("s_waitcnt lgkmcnt(0)" ::: "memory");   // LDS writes visible
    __builtin_amdgcn_s_barrier();                        // vmcnt stays in flight
#pragma unroll
    for (int ks = 0; ks < 2; ks++) {
      int kk = ks * 32 + kb * 8;
      bf16x8 bfr = *(const bf16x8*)&BT[p][swz(w * 16 + m, kk)];
      bf16x8 a0  = *(const bf16x8*)&AT[p][swz(m, kk)];
      bf16x8 a1  = *(const bf16x8*)&AT[p][swz(16 + m, kk)];
      acc0 = __builtin_amdgcn_mfma_f32_16x16x32_bf16(a0, bfr, acc0, 0, 0, 0);
      acc1 = __builtin_amdgcn_mfma_f32_16x16x32_bf16(a1, bfr, acc1, 0, 0, 0);
    }
  }
  int col = c0 + w * 16 + m;
  float bz = bias[e * NTOT + col];
#pragma unroll
  for (int r2 = 0; r2 < 4; r2++) {            // C/D: col=lane&15, row=kb*4+r (+16)
    int r0 = kb * 4 + r2;
    if (r0 < nrow) {
      int tok = order[ts + r0];
      float v = acc0[r2] + bz; v = v > 0.f ? v : 0.f;
      if constexpr (OUT_BF16)
        ((unsigned short*)outp)[(size_t)tok * NTOT + col] = f2bf(v);
      else
        ((float*)outp)[(size_t)tok * NTOT + col] = v;
    }
    int r1 = 16 + kb * 4 + r2;
    if (r1 < nrow) {
      int tok = order[ts + r1];
      float v = acc1[r2] + bz; v = v > 0.f ? v : 0.f;
      if constexpr (OUT_BF16)
        ((unsigned short*)outp)[(size_t)tok * NTOT + col] = f2bf(v);
      else
        ((float*)outp)[(size_t)tok * NTOT + col] = v;
    }
  }
}

// ---------------- K2: persistent GEMM, per-expert L1->L2 pipeline --------------------
// 256 blocks (1/CU; capacity >=2/CU so all co-resident -> spins always progress).
// Block bid: class xcd=bid&7, lane r=bid>>3 (0..31). L1 slots s=r,r+32,..<ntc*2
// (y = s<ntc?0:1). After each L1 tile: syncthreads (barrier drains vmcnt -> stores
// in L2) + release atomicAdd l1done[e]. L2 slots s=r,r+32,..<ntc*8: relaxed-spin
// until l1done[e]==2*nt[e], single acquire load (one cache-inv per tile), compute.
__global__ __launch_bounds__(512, 2) void moe_persist_kernel(
    const float* __restrict__ x, const float* __restrict__ w1,
    const float* __restrict__ b1, const float* __restrict__ w2,
    const float* __restrict__ b2, unsigned short* __restrict__ hb,
    float* __restrict__ out, const int* __restrict__ meta,
    const int* __restrict__ order, int* __restrict__ l1done) {
  __shared__ unsigned short AT[2][32 * 72];   //  9.2 KB
  __shared__ unsigned short BT[2][128 * 72];  // 36.9 KB
  int bid = blockIdx.x, xcd = bid & 7, r = bid >> 3;   // r in 0..31
  int ntc = meta[xcd];
  int t = threadIdx.x;
  // ---- L1 phase: h = relu(x @ W1[e] + b1[e]) ----
  for (int s = r; s < ntc * 2; s += 32) {
    int y = (s < ntc) ? 0 : 1, rank = (s < ntc) ? s : s - ntc;
    int info = meta[8 + xcd + 8 * rank];
    int e = info >> 24, nrow = (info >> 16) & 0xff, ts = info & 0xffff;
    gemm_tile<DDIM, HDIM, true, true>(x, w1, b1, order, hb, e, nrow, ts, y * 128, AT, BT);
    __syncthreads();   // all waves' hb stores drained (barrier waitcnt) + LDS reuse
    if (t == 0)
      __hip_atomic_fetch_add(&l1done[e], 1, __ATOMIC_RELEASE, __HIP_MEMORY_SCOPE_AGENT);
  }
  // ---- L2 phase: out = relu(h @ W2[e] + b2[e]), gated per expert ----
  for (int s = r; s < ntc * 8; s += 32) {
    int y = s / ntc, rank = s - y * ntc;
    int info = meta[8 + xcd + 8 * rank];
    int e = info >> 24, nrow = (info >> 16) & 0xff, ts = info & 0xffff;
    if (t == 0) {
      int need = 2 * meta[1096 + e];
      while (__hip_atomic_load(&l1done[e], __ATOMIC_RELAXED, __HIP_MEMORY_SCOPE_AGENT) < need)
        __builtin_amdgcn_s_sleep(8);
      (void)__hip_atomic_load(&l1done[e], __ATOMIC_ACQUIRE, __HIP_MEMORY_SCOPE_AGENT);
    }
    __syncthreads();   // block proceeds only after acquire; also LDS reuse guard
    gemm_tile<HDIM, DDIM, false, false>(hb, w2, b2, order, out, e, nrow, ts, y * 128, AT, BT);
    __syncthreads();   // LDS reuse guard before next tile's staging
  }
}

// ---------------- launch ----------------

extern "C" void kernel_launch(void* const* d_in, const int* in_sizes, int n_in,
                              void* d_out, int out_size, void* d_ws, size_t ws_size,
                              hipStream_t stream) {
  const float* x  = (const float*)d_in[0];
  const float* rw = (const float*)d_in[1];
  const float* rb = (const float*)d_in[2];
  const float* w1 = (const float*)d_in[3];
  const float* b1 = (const float*)d_in[4];
  const float* w2 = (const float*)d_in[5];
  const float* b2 = (const float*)d_in[6];
  float* out = (float*)d_out;

  char* ws = (char*)d_ws;
  unsigned short* hb = (unsigned short*)(ws + 0);   // 2,097,152  h bf16 [N][H]
  int* routed = (int*)(ws + 2097152);               //    16,384
  int* order  = (int*)(ws + 2113536);               //    16,384
  int* meta   = (int*)(ws + 2129920);               //  4,608: [0..7] ntc, [8..1095] slots,
                                                    //         [1096..1127] nt[e]
  int* done   = (int*)(ws + 2134528);               //      4  (zeroed each call)
  int* l1done = (int*)(ws + 2134532);               //    128  (zeroed each call)

  hipMemsetAsync(done, 0, 4 + 128, stream);
  router_scan_kernel<<<dim3(256), dim3(512), 0, stream>>>(
      x, rw, rb, routed, meta, order, done);
  moe_persist_kernel<<<dim3(256), dim3(512), 0, stream>>>(
      x, w1, b1, w2, b2, hb, out, meta, order, l1done);
}

// Round 11
// 63.663 us; speedup vs baseline: 1.5263x; 1.5263x over previous
//
#include <hip/hip_runtime.h>

// MoE block: B=128,K=32 -> N=4096 tokens, D=1024, H=256, E=32, top-1 routing.
// out[tok] = relu(relu(x[tok] @ W1[e] + b1[e]) @ W2[e] + b2[e]), e = argmax(x@rw.T+rb)
// 3 kernels (+1 tiny memset): router+tail-scan (R7/R10-proven fence pattern),
// expert_gemm<L1>, expert_gemm<L2> (R9 split structure: TLP across blocks is
// load-bearing -- R10's persistent 1-block/CU variant proved latency-bound at
// MfmaUtil 2.2%). B staging now b128 writes at the exact LDS bank floor
// (R10 counter: 2.97M conflicts from the b64 form's 2x-over-floor pattern).

#define N_TOK 4096
#define DDIM  1024
#define HDIM  256
#define NEXP  32
#define TPX   136          // max 32-token tiles per XCD class (<=132 worst case)

typedef __attribute__((ext_vector_type(8))) short bf16x8;   // 8 bf16 in 4 VGPRs
typedef __attribute__((ext_vector_type(4))) float f32x4;

__device__ __forceinline__ unsigned short f2bf(float f) {   // RNE f32->bf16
  union { float f; unsigned u; } v; v.f = f;
  unsigned r = v.u + 0x7FFFu + ((v.u >> 16) & 1u);
  return (unsigned short)(r >> 16);
}
__device__ __forceinline__ float bf2f(unsigned short h) {
  union { unsigned u; float f; } v; v.u = ((unsigned)h) << 16;
  return v.f;
}
// LDS tile addressing: row-major stride 72 shorts, kk bits 3-5 XORed with (row>>3)&7.
// b128 frag reads ~floor; b64 A-writes floor; b128 B-writes exact floor (R10 fix).
__device__ __forceinline__ int swz(int row, int kk) {
  return row * 72 + (kk ^ (((row >> 3) & 7) << 3));
}

// ---------------- K1: router + tail-block scan (R7/R10-proven fence pattern) ---------
// Router: 8 waves per 16-token tile, wave w owns K window [w*128,+128); fp32-accurate
// logits via 4-term bf16 hi/lo split MFMA. Last block (threadfence + done counter)
// builds histogram, XCD-pinned 32-token tile slots, and the order array.
__global__ __launch_bounds__(512) void router_scan_kernel(
    const float* __restrict__ x, const float* __restrict__ rw,
    const float* __restrict__ rb, int* __restrict__ routed,
    int* __restrict__ meta, int* __restrict__ order, int* __restrict__ done) {
  __shared__ float red[8][64][8];
  __shared__ int scnt[NEXP];
  __shared__ int scur[NEXP];
  __shared__ int lastflag;
  int b = blockIdx.x;
  int t = threadIdx.x, w = t >> 6, l = t & 63;
  int m = l & 15, kb = l >> 4;
  int tok = b * 16 + m;
  int kbase = w * 128;
  bf16x8 wh[2][4], wl[2][4];              // rw rows m, m+16; this thread's k-window
#pragma unroll
  for (int h = 0; h < 2; h++) {
    const float* wp = rw + (size_t)(m + h * 16) * DDIM + kbase + kb * 8;
#pragma unroll
    for (int q = 0; q < 4; q++) {
      float4 f0 = *(const float4*)(wp + q * 32);
      float4 f1 = *(const float4*)(wp + q * 32 + 4);
      float fv[8] = {f0.x, f0.y, f0.z, f0.w, f1.x, f1.y, f1.z, f1.w};
      bf16x8 hi, lo;
#pragma unroll
      for (int i = 0; i < 8; i++) {
        unsigned short hh = f2bf(fv[i]);
        hi[i] = (short)hh;
        lo[i] = (short)f2bf(fv[i] - bf2f(hh));
      }
      wh[h][q] = hi; wl[h][q] = lo;
    }
  }
  const float* xrow = x + (size_t)tok * DDIM + kbase + kb * 8;
  f32x4 acc0 = {0.f,0.f,0.f,0.f}, acc1 = {0.f,0.f,0.f,0.f};
#pragma unroll
  for (int q = 0; q < 4; q++) {
    float4 xa = *(const float4*)(xrow + q * 32);
    float4 xc = *(const float4*)(xrow + q * 32 + 4);
    float xv[8] = {xa.x, xa.y, xa.z, xa.w, xc.x, xc.y, xc.z, xc.w};
    bf16x8 xhi, xlo;
#pragma unroll
    for (int i = 0; i < 8; i++) {
      unsigned short hh = f2bf(xv[i]);
      xhi[i] = (short)hh;
      xlo[i] = (short)f2bf(xv[i] - bf2f(hh));
    }
    acc0 = __builtin_amdgcn_mfma_f32_16x16x32_bf16(xhi, wh[0][q], acc0, 0, 0, 0);
    acc0 = __builtin_amdgcn_mfma_f32_16x16x32_bf16(xlo, wh[0][q], acc0, 0, 0, 0);
    acc0 = __builtin_amdgcn_mfma_f32_16x16x32_bf16(xhi, wl[0][q], acc0, 0, 0, 0);
    acc0 = __builtin_amdgcn_mfma_f32_16x16x32_bf16(xlo, wl[0][q], acc0, 0, 0, 0);
    acc1 = __builtin_amdgcn_mfma_f32_16x16x32_bf16(xhi, wh[1][q], acc1, 0, 0, 0);
    acc1 = __builtin_amdgcn_mfma_f32_16x16x32_bf16(xlo, wh[1][q], acc1, 0, 0, 0);
    acc1 = __builtin_amdgcn_mfma_f32_16x16x32_bf16(xhi, wl[1][q], acc1, 0, 0, 0);
    acc1 = __builtin_amdgcn_mfma_f32_16x16x32_bf16(xlo, wl[1][q], acc1, 0, 0, 0);
  }
  *(f32x4*)&red[w][l][0] = acc0;
  *(f32x4*)&red[w][l][4] = acc1;
  __syncthreads();
  if (w == 0) {
    f32x4 s0 = {0.f,0.f,0.f,0.f}, s1 = {0.f,0.f,0.f,0.f};
#pragma unroll
    for (int ww = 0; ww < 8; ww++) {
      s0 += *(const f32x4*)&red[ww][l][0];
      s1 += *(const f32x4*)&red[ww][l][4];
    }
    float rb0 = rb[m], rb1 = rb[16 + m];
#pragma unroll
    for (int r = 0; r < 4; r++) {       // token row = kb*4+r
      float v0 = s0[r] + rb0;
      float v1 = s1[r] + rb1;
      float val = v0; int idx = m;
      if (v1 > v0) { val = v1; idx = 16 + m; }   // ties -> smaller e (np.argmax)
#pragma unroll
      for (int s = 1; s < 16; s <<= 1) {
        float ov = __shfl_xor(val, s);
        int oi = __shfl_xor(idx, s);
        if (ov > val || (ov == val && oi < idx)) { val = ov; idx = oi; }
      }
      if (m == 0) routed[b * 16 + kb * 4 + r] = idx;
    }
  }
  // ---- tail-block scan: last block to finish builds meta/order ----
  __syncthreads();
  if (t == 0) {
    __threadfence();                    // release: my routed writes visible
    int v = atomicAdd(done, 1);         // device-scope
    lastflag = (v == 255);
    if (lastflag) __threadfence();      // acquire: everyone's routed visible
  }
  __syncthreads();
  if (!lastflag) return;
  if (t < NEXP) scnt[t] = 0;
  __syncthreads();
  for (int n = t; n < N_TOK; n += 512) atomicAdd(&scnt[routed[n]], 1);
  __syncthreads();
  if (t < NEXP) {                       // lanes 0..31 of wave 0
    int c = scnt[t];
    int nt = (c + 31) >> 5;             // 32-token tiles
    int ic = c;
#pragma unroll
    for (int s = 1; s < NEXP; s <<= 1) {
      int pc = __shfl_up(ic, s);
      if (t >= s) ic += pc;
    }
    int off = ic - c;
    scur[t] = off;
    int cls = t & 7, pos = t >> 3;      // XCD class, rank-in-class position
    int rank = 0;
#pragma unroll
    for (int j = 0; j < 4; j++) {
      int v = __shfl(nt, cls + j * 8);
      if (pos > j) rank += v;
    }
    for (int s2 = 0; s2 < nt; s2++) {
      int nr = c - s2 * 32; if (nr > 32) nr = 32;
      meta[8 + cls + 8 * (rank + s2)] = (t << 24) | (nr << 16) | (off + s2 * 32);
    }
    if (pos == 3) meta[cls] = rank + nt;  // per-class tile count
  }
  __syncthreads();
  for (int n = t; n < N_TOK; n += 512) {
    int e = routed[n];
    int p = atomicAdd(&scur[e], 1);     // intra-expert order arbitrary: out invariant
    order[p] = n;
  }
}

// ---------------- K2/K3: grouped GEMM with in-LDS transpose of fp32 weights ----------
// Block 512 thr = 8 waves, tile 32 tok x 128 cols; per 64-k chunk: stage A (gathered
// rows, fp32->bf16 for L1) and B (W[k][n] fp32 -> bf16 transposed) into swizzled LDS.
// Depth-2 register prefetch; vmcnt stays in flight across the barrier. B staging:
// thread owns column bcn=t&127, k-groups kg=t>>7 and kg+4; packs 8 bf16 -> b128
// ds_write at the exact bank floor (octet covers all 32 banks once). 1-D grid,
// y-OUTERMOST: one 128-col weight slab per expert live per XCD at a time.
template <int KDIM, int NTOT, bool A_FP32, bool OUT_BF16>
__global__ __launch_bounds__(512) void expert_gemm_kernel(
    const void* __restrict__ a_src, const float* __restrict__ wsrc,
    const float* __restrict__ bias, const int* __restrict__ meta,
    const int* __restrict__ order, void* __restrict__ outp) {
  constexpr int NCH = KDIM / 64;
  constexpr int NSLAB = NTOT / 128;
  __shared__ unsigned short AT[2][32 * 72];   //  9.2 KB
  __shared__ unsigned short BT[2][128 * 72];  // 36.9 KB
  int bid = blockIdx.x, xcd = bid & 7, r = bid >> 3;
  int ntc = meta[xcd];
  if (r >= ntc * NSLAB) return;
  int y = r / ntc, rank = r - y * ntc;
  int info = meta[8 + xcd + 8 * rank];
  int e = info >> 24, nrow = (info >> 16) & 0xff, ts = info & 0xffff;
  int c0 = y * 128;
  int t = threadIdx.x, w = t >> 6, l = t & 63, m = l & 15, kb = l >> 4;
  // staging roles: A = 32 rows x 64 kk (16 thr/row, float4/ushort4 each);
  //                B = col bcn=t&127, k-groups kg=t>>7 and kg+4 (8 k's each)
  int atr = t >> 4, ak4 = (t & 15) * 4;
  int bcn = t & 127, bkg = t >> 7;            // bkg in 0..3
  int atok = order[ts + (atr < nrow ? atr : nrow - 1)];   // clamp: masked at store
  const float* aF = (const float*)a_src + (size_t)atok * KDIM + ak4;
  const unsigned short* aH = (const unsigned short*)a_src + (size_t)atok * KDIM + ak4;
  const float* bS = wsrc + (size_t)e * KDIM * NTOT + c0 + bcn;

  float4 nAf[2]; ushort4 nAh[2];
  float nB[2][2][8];                          // all indices compile-time (full unroll)
  auto LOADC = [&](int c, int rbuf) {
    if constexpr (A_FP32) nAf[rbuf] = *(const float4*)(aF + c * 64);
    else                  nAh[rbuf] = *(const ushort4*)(aH + c * 64);
#pragma unroll
    for (int u = 0; u < 2; u++)
#pragma unroll
      for (int j = 0; j < 8; j++)
        nB[rbuf][u][j] = bS[(size_t)(c * 64 + (bkg + 4 * u) * 8 + j) * NTOT];
  };

  f32x4 acc0 = {0.f,0.f,0.f,0.f}, acc1 = {0.f,0.f,0.f,0.f};
  LOADC(0, 0);
  LOADC(1, 1);
#pragma unroll
  for (int c = 0; c < NCH; c++) {
    const int p = c & 1;
    ushort4 av;
    if constexpr (A_FP32) {
      av.x = f2bf(nAf[p].x); av.y = f2bf(nAf[p].y);
      av.z = f2bf(nAf[p].z); av.w = f2bf(nAf[p].w);
    } else av = nAh[p];
    *(ushort4*)&AT[p][swz(atr, ak4)] = av;    // b64: bank floor
#pragma unroll
    for (int u = 0; u < 2; u++) {             // B writes b128: exact bank floor
      bf16x8 pv;
#pragma unroll
      for (int j = 0; j < 8; j++) pv[j] = (short)f2bf(nB[p][u][j]);
      *(bf16x8*)&BT[p][swz(bcn, (bkg + 4 * u) * 8)] = pv;
    }
    if (c + 2 < NCH) LOADC(c + 2, p);         // WAR-safe: ds_writes read regs at issue
    asm volatile("s_waitcnt lgkmcnt(0)" ::: "memory");   // LDS writes visible
    __builtin_amdgcn_s_barrier();                        // vmcnt stays in flight
#pragma unroll
    for (int ks = 0; ks < 2; ks++) {
      int kk = ks * 32 + kb * 8;
      bf16x8 bfr = *(const bf16x8*)&BT[p][swz(w * 16 + m, kk)];
      bf16x8 a0  = *(const bf16x8*)&AT[p][swz(m, kk)];
      bf16x8 a1  = *(const bf16x8*)&AT[p][swz(16 + m, kk)];
      acc0 = __builtin_amdgcn_mfma_f32_16x16x32_bf16(a0, bfr, acc0, 0, 0, 0);
      acc1 = __builtin_amdgcn_mfma_f32_16x16x32_bf16(a1, bfr, acc1, 0, 0, 0);
    }
  }
  int col = c0 + w * 16 + m;
  float bz = bias[e * NTOT + col];
#pragma unroll
  for (int r2 = 0; r2 < 4; r2++) {            // C/D: col=lane&15, row=kb*4+r (+16)
    int r0 = kb * 4 + r2;
    if (r0 < nrow) {
      int tok = order[ts + r0];
      float v = acc0[r2] + bz; v = v > 0.f ? v : 0.f;
      if constexpr (OUT_BF16)
        ((unsigned short*)outp)[(size_t)tok * NTOT + col] = f2bf(v);
      else
        ((float*)outp)[(size_t)tok * NTOT + col] = v;
    }
    int r1 = 16 + kb * 4 + r2;
    if (r1 < nrow) {
      int tok = order[ts + r1];
      float v = acc1[r2] + bz; v = v > 0.f ? v : 0.f;
      if constexpr (OUT_BF16)
        ((unsigned short*)outp)[(size_t)tok * NTOT + col] = f2bf(v);
      else
        ((float*)outp)[(size_t)tok * NTOT + col] = v;
    }
  }
}

// ---------------- launch ----------------

extern "C" void kernel_launch(void* const* d_in, const int* in_sizes, int n_in,
                              void* d_out, int out_size, void* d_ws, size_t ws_size,
                              hipStream_t stream) {
  const float* x  = (const float*)d_in[0];
  const float* rw = (const float*)d_in[1];
  const float* rb = (const float*)d_in[2];
  const float* w1 = (const float*)d_in[3];
  const float* b1 = (const float*)d_in[4];
  const float* w2 = (const float*)d_in[5];
  const float* b2 = (const float*)d_in[6];
  float* out = (float*)d_out;

  char* ws = (char*)d_ws;
  unsigned short* hb = (unsigned short*)(ws + 0);   // 2,097,152  h bf16 [N][H]
  int* routed = (int*)(ws + 2097152);               //    16,384
  int* order  = (int*)(ws + 2113536);               //    16,384
  int* meta   = (int*)(ws + 2129920);               //     4,608
  int* done   = (int*)(ws + 2134528);               //         4 (zeroed each call)

  hipMemsetAsync(done, 0, 4, stream);
  router_scan_kernel<<<dim3(256), dim3(512), 0, stream>>>(
      x, rw, rb, routed, meta, order, done);
  expert_gemm_kernel<DDIM, HDIM, true, true>
      <<<dim3(8 * TPX * (HDIM / 128)), dim3(512), 0, stream>>>(
      x, w1, b1, meta, order, hb);
  expert_gemm_kernel<HDIM, DDIM, false, false>
      <<<dim3(8 * TPX * (DDIM / 128)), dim3(512), 0, stream>>>(
      hb, w2, b2, meta, order, out);
}

// Round 12
// 54.303 us; speedup vs baseline: 1.7894x; 1.1724x over previous
//
#include <hip/hip_runtime.h>

// MoE block: B=128,K=32 -> N=4096 tokens, D=1024, H=256, E=32, top-1 routing.
// out[tok] = relu(relu(x[tok] @ W1[e] + b1[e]) @ W2[e] + b2[e]), e = argmax(x@rw.T+rb)
// 4 launches (R9-proven frame; NO tiny memset -- a 4B hipMemsetAsync dispatch costs
// ~40us in-graph, measured R7/R10/R11): router, scan_scatter, expert_gemm<L1>,
// expert_gemm<L2>. Weights consumed in ORIGINAL fp32 [K][N] layout; transpose+
// bf16-cvt during LDS staging. Depth-2 register prefetch in the K-loop. B staging
// via b128 ds_writes at the exact bank floor (R9's b64 form was 2x over floor ->
// 2.97M conflicts in R10's counter).

#define N_TOK 4096
#define DDIM  1024
#define HDIM  256
#define NEXP  32
#define TPX   136          // max 32-token tiles per XCD class (<=132 worst case)

typedef __attribute__((ext_vector_type(8))) short bf16x8;   // 8 bf16 in 4 VGPRs
typedef __attribute__((ext_vector_type(4))) float f32x4;

__device__ __forceinline__ unsigned short f2bf(float f) {   // RNE f32->bf16
  union { float f; unsigned u; } v; v.f = f;
  unsigned r = v.u + 0x7FFFu + ((v.u >> 16) & 1u);
  return (unsigned short)(r >> 16);
}
__device__ __forceinline__ float bf2f(unsigned short h) {
  union { unsigned u; float f; } v; v.u = ((unsigned)h) << 16;
  return v.f;
}
// LDS tile addressing: row-major stride 72 shorts, kk bits 3-5 XORed with (row>>3)&7.
// b128 frag reads ~floor; b64 A-writes floor; b128 B-writes exact floor.
__device__ __forceinline__ int swz(int row, int kk) {
  return row * 72 + (kk ^ (((row >> 3) & 7) << 3));
}

// ---------------- K1: router (fp32-accurate logits via 4-term bf16 split MFMA) --------
// 512 thr = 8 waves per 16-token tile; wave w owns K window [w*128,+128).
__global__ __launch_bounds__(512) void router_kernel(
    const float* __restrict__ x, const float* __restrict__ rw,
    const float* __restrict__ rb, int* __restrict__ routed) {
  __shared__ float red[8][64][8];
  int b = blockIdx.x;
  int t = threadIdx.x, w = t >> 6, l = t & 63;
  int m = l & 15, kb = l >> 4;
  int tok = b * 16 + m;
  int kbase = w * 128;
  bf16x8 wh[2][4], wl[2][4];              // rw rows m, m+16; this thread's k-window
#pragma unroll
  for (int h = 0; h < 2; h++) {
    const float* wp = rw + (size_t)(m + h * 16) * DDIM + kbase + kb * 8;
#pragma unroll
    for (int q = 0; q < 4; q++) {
      float4 f0 = *(const float4*)(wp + q * 32);
      float4 f1 = *(const float4*)(wp + q * 32 + 4);
      float fv[8] = {f0.x, f0.y, f0.z, f0.w, f1.x, f1.y, f1.z, f1.w};
      bf16x8 hi, lo;
#pragma unroll
      for (int i = 0; i < 8; i++) {
        unsigned short hh = f2bf(fv[i]);
        hi[i] = (short)hh;
        lo[i] = (short)f2bf(fv[i] - bf2f(hh));
      }
      wh[h][q] = hi; wl[h][q] = lo;
    }
  }
  const float* xrow = x + (size_t)tok * DDIM + kbase + kb * 8;
  f32x4 acc0 = {0.f,0.f,0.f,0.f}, acc1 = {0.f,0.f,0.f,0.f};
#pragma unroll
  for (int q = 0; q < 4; q++) {
    float4 xa = *(const float4*)(xrow + q * 32);
    float4 xc = *(const float4*)(xrow + q * 32 + 4);
    float xv[8] = {xa.x, xa.y, xa.z, xa.w, xc.x, xc.y, xc.z, xc.w};
    bf16x8 xhi, xlo;
#pragma unroll
    for (int i = 0; i < 8; i++) {
      unsigned short hh = f2bf(xv[i]);
      xhi[i] = (short)hh;
      xlo[i] = (short)f2bf(xv[i] - bf2f(hh));
    }
    acc0 = __builtin_amdgcn_mfma_f32_16x16x32_bf16(xhi, wh[0][q], acc0, 0, 0, 0);
    acc0 = __builtin_amdgcn_mfma_f32_16x16x32_bf16(xlo, wh[0][q], acc0, 0, 0, 0);
    acc0 = __builtin_amdgcn_mfma_f32_16x16x32_bf16(xhi, wl[0][q], acc0, 0, 0, 0);
    acc0 = __builtin_amdgcn_mfma_f32_16x16x32_bf16(xlo, wl[0][q], acc0, 0, 0, 0);
    acc1 = __builtin_amdgcn_mfma_f32_16x16x32_bf16(xhi, wh[1][q], acc1, 0, 0, 0);
    acc1 = __builtin_amdgcn_mfma_f32_16x16x32_bf16(xlo, wh[1][q], acc1, 0, 0, 0);
    acc1 = __builtin_amdgcn_mfma_f32_16x16x32_bf16(xhi, wl[1][q], acc1, 0, 0, 0);
    acc1 = __builtin_amdgcn_mfma_f32_16x16x32_bf16(xlo, wl[1][q], acc1, 0, 0, 0);
  }
  *(f32x4*)&red[w][l][0] = acc0;
  *(f32x4*)&red[w][l][4] = acc1;
  __syncthreads();
  if (w == 0) {
    f32x4 s0 = {0.f,0.f,0.f,0.f}, s1 = {0.f,0.f,0.f,0.f};
#pragma unroll
    for (int ww = 0; ww < 8; ww++) {
      s0 += *(const f32x4*)&red[ww][l][0];
      s1 += *(const f32x4*)&red[ww][l][4];
    }
    float rb0 = rb[m], rb1 = rb[16 + m];
#pragma unroll
    for (int r = 0; r < 4; r++) {       // token row = kb*4+r
      float v0 = s0[r] + rb0;
      float v1 = s1[r] + rb1;
      float val = v0; int idx = m;
      if (v1 > v0) { val = v1; idx = 16 + m; }   // ties -> smaller e (np.argmax)
#pragma unroll
      for (int s = 1; s < 16; s <<= 1) {
        float ov = __shfl_xor(val, s);
        int oi = __shfl_xor(idx, s);
        if (ov > val || (ov == val && oi < idx)) { val = ov; idx = oi; }
      }
      if (m == 0) routed[b * 16 + kb * 4 + r] = idx;
    }
  }
}

// ---------------- K2: histogram + scan + XCD-pinned tile slots + scatter --------------
// meta[0..7] = tiles per XCD class; meta[8 + cls + 8*rank] = (e<<24)|(nrow<<16)|start.
// All tiles of expert e sit at consecutive ranks of class e&7 (L2 temporal locality).
__global__ __launch_bounds__(512) void scan_scatter_kernel(const int* __restrict__ routed,
    int* __restrict__ meta, int* __restrict__ order) {
  __shared__ int scnt[NEXP];
  __shared__ int scur[NEXP];
  int t = threadIdx.x;
  if (t < NEXP) scnt[t] = 0;
  __syncthreads();
  for (int n = t; n < N_TOK; n += 512) atomicAdd(&scnt[routed[n]], 1);
  __syncthreads();
  if (t < NEXP) {                           // lanes 0..31 of wave 0
    int c = scnt[t];
    int nt = (c + 31) >> 5;                 // 32-token tiles
    int ic = c;
#pragma unroll
    for (int s = 1; s < NEXP; s <<= 1) {
      int pc = __shfl_up(ic, s);
      if (t >= s) ic += pc;
    }
    int off = ic - c;
    scur[t] = off;
    int cls = t & 7, pos = t >> 3;          // XCD class, rank-in-class position
    int rank = 0;
#pragma unroll
    for (int j = 0; j < 4; j++) {
      int v = __shfl(nt, cls + j * 8);
      if (pos > j) rank += v;
    }
    for (int s2 = 0; s2 < nt; s2++) {
      int nr = c - s2 * 32; if (nr > 32) nr = 32;
      meta[8 + cls + 8 * (rank + s2)] = (t << 24) | (nr << 16) | (off + s2 * 32);
    }
    if (pos == 3) meta[cls] = rank + nt;    // per-class tile count
  }
  __syncthreads();
  for (int n = t; n < N_TOK; n += 512) {
    int e = routed[n];
    int p = atomicAdd(&scur[e], 1);         // intra-expert order arbitrary: out invariant
    order[p] = n;
  }
}

// ---------------- K3/K4: grouped GEMM with in-LDS transpose of fp32 weights ----------
// Block 512 thr = 8 waves, tile 32 tok x 128 cols; per 64-k chunk: stage A (gathered
// rows, fp32->bf16 for L1) and B (W[k][n] fp32 -> bf16 transposed) into swizzled LDS.
// Depth-2 register prefetch; vmcnt stays in flight across the barrier. B staging:
// thread owns column bcn=t&127, k-groups kg=t>>7 and kg+4; packs 8 bf16 -> b128
// ds_write at the exact bank floor. 1-D grid, y-OUTERMOST: one 128-col weight slab
// per expert live per XCD at a time.
template <int KDIM, int NTOT, bool A_FP32, bool OUT_BF16>
__global__ __launch_bounds__(512) void expert_gemm_kernel(
    const void* __restrict__ a_src, const float* __restrict__ wsrc,
    const float* __restrict__ bias, const int* __restrict__ meta,
    const int* __restrict__ order, void* __restrict__ outp) {
  constexpr int NCH = KDIM / 64;
  constexpr int NSLAB = NTOT / 128;
  __shared__ unsigned short AT[2][32 * 72];   //  9.2 KB
  __shared__ unsigned short BT[2][128 * 72];  // 36.9 KB
  int bid = blockIdx.x, xcd = bid & 7, r = bid >> 3;
  int ntc = meta[xcd];
  if (r >= ntc * NSLAB) return;
  int y = r / ntc, rank = r - y * ntc;
  int info = meta[8 + xcd + 8 * rank];
  int e = info >> 24, nrow = (info >> 16) & 0xff, ts = info & 0xffff;
  int c0 = y * 128;
  int t = threadIdx.x, w = t >> 6, l = t & 63, m = l & 15, kb = l >> 4;
  // staging roles: A = 32 rows x 64 kk (16 thr/row, float4/ushort4 each);
  //                B = col bcn=t&127, k-groups kg=t>>7 and kg+4 (8 k's each)
  int atr = t >> 4, ak4 = (t & 15) * 4;
  int bcn = t & 127, bkg = t >> 7;            // bkg in 0..3
  int atok = order[ts + (atr < nrow ? atr : nrow - 1)];   // clamp: masked at store
  const float* aF = (const float*)a_src + (size_t)atok * KDIM + ak4;
  const unsigned short* aH = (const unsigned short*)a_src + (size_t)atok * KDIM + ak4;
  const float* bS = wsrc + (size_t)e * KDIM * NTOT + c0 + bcn;

  float4 nAf[2]; ushort4 nAh[2];
  float nB[2][2][8];                          // all indices compile-time (full unroll)
  auto LOADC = [&](int c, int rbuf) {
    if constexpr (A_FP32) nAf[rbuf] = *(const float4*)(aF + c * 64);
    else                  nAh[rbuf] = *(const ushort4*)(aH + c * 64);
#pragma unroll
    for (int u = 0; u < 2; u++)
#pragma unroll
      for (int j = 0; j < 8; j++)
        nB[rbuf][u][j] = bS[(size_t)(c * 64 + (bkg + 4 * u) * 8 + j) * NTOT];
  };

  f32x4 acc0 = {0.f,0.f,0.f,0.f}, acc1 = {0.f,0.f,0.f,0.f};
  LOADC(0, 0);
  LOADC(1, 1);
#pragma unroll
  for (int c = 0; c < NCH; c++) {
    const int p = c & 1;
    ushort4 av;
    if constexpr (A_FP32) {
      av.x = f2bf(nAf[p].x); av.y = f2bf(nAf[p].y);
      av.z = f2bf(nAf[p].z); av.w = f2bf(nAf[p].w);
    } else av = nAh[p];
    *(ushort4*)&AT[p][swz(atr, ak4)] = av;    // b64: bank floor
#pragma unroll
    for (int u = 0; u < 2; u++) {             // B writes b128: exact bank floor
      bf16x8 pv;
#pragma unroll
      for (int j = 0; j < 8; j++) pv[j] = (short)f2bf(nB[p][u][j]);
      *(bf16x8*)&BT[p][swz(bcn, (bkg + 4 * u) * 8)] = pv;
    }
    if (c + 2 < NCH) LOADC(c + 2, p);         // WAR-safe: ds_writes read regs at issue
    asm volatile("s_waitcnt lgkmcnt(0)" ::: "memory");   // LDS writes visible
    __builtin_amdgcn_s_barrier();                        // vmcnt stays in flight
#pragma unroll
    for (int ks = 0; ks < 2; ks++) {
      int kk = ks * 32 + kb * 8;
      bf16x8 bfr = *(const bf16x8*)&BT[p][swz(w * 16 + m, kk)];
      bf16x8 a0  = *(const bf16x8*)&AT[p][swz(m, kk)];
      bf16x8 a1  = *(const bf16x8*)&AT[p][swz(16 + m, kk)];
      acc0 = __builtin_amdgcn_mfma_f32_16x16x32_bf16(a0, bfr, acc0, 0, 0, 0);
      acc1 = __builtin_amdgcn_mfma_f32_16x16x32_bf16(a1, bfr, acc1, 0, 0, 0);
    }
    // reads of buf p retire before next chunk's lgkmcnt(0)+barrier -> 1 barrier safe;
    // buf p is rewritten only at c+2, after that barrier.
  }
  int col = c0 + w * 16 + m;
  float bz = bias[e * NTOT + col];
#pragma unroll
  for (int r2 = 0; r2 < 4; r2++) {            // C/D: col=lane&15, row=kb*4+r (+16)
    int r0 = kb * 4 + r2;
    if (r0 < nrow) {
      int tok = order[ts + r0];
      float v = acc0[r2] + bz; v = v > 0.f ? v : 0.f;
      if constexpr (OUT_BF16)
        ((unsigned short*)outp)[(size_t)tok * NTOT + col] = f2bf(v);
      else
        ((float*)outp)[(size_t)tok * NTOT + col] = v;
    }
    int r1 = 16 + kb * 4 + r2;
    if (r1 < nrow) {
      int tok = order[ts + r1];
      float v = acc1[r2] + bz; v = v > 0.f ? v : 0.f;
      if constexpr (OUT_BF16)
        ((unsigned short*)outp)[(size_t)tok * NTOT + col] = f2bf(v);
      else
        ((float*)outp)[(size_t)tok * NTOT + col] = v;
    }
  }
}

// ---------------- launch ----------------

extern "C" void kernel_launch(void* const* d_in, const int* in_sizes, int n_in,
                              void* d_out, int out_size, void* d_ws, size_t ws_size,
                              hipStream_t stream) {
  const float* x  = (const float*)d_in[0];
  const float* rw = (const float*)d_in[1];
  const float* rb = (const float*)d_in[2];
  const float* w1 = (const float*)d_in[3];
  const float* b1 = (const float*)d_in[4];
  const float* w2 = (const float*)d_in[5];
  const float* b2 = (const float*)d_in[6];
  float* out = (float*)d_out;

  char* ws = (char*)d_ws;
  unsigned short* hb = (unsigned short*)(ws + 0);   // 2,097,152  h bf16 [N][H]
  int* routed = (int*)(ws + 2097152);               //    16,384
  int* order  = (int*)(ws + 2113536);               //    16,384
  int* meta   = (int*)(ws + 2129920);               //     4,608

  router_kernel<<<dim3(256), dim3(512), 0, stream>>>(x, rw, rb, routed);
  scan_scatter_kernel<<<dim3(1), dim3(512), 0, stream>>>(routed, meta, order);
  expert_gemm_kernel<DDIM, HDIM, true, true>
      <<<dim3(8 * TPX * (HDIM / 128)), dim3(512), 0, stream>>>(
      x, w1, b1, meta, order, hb);
  expert_gemm_kernel<HDIM, DDIM, false, false>
      <<<dim3(8 * TPX * (DDIM / 128)), dim3(512), 0, stream>>>(
      hb, w2, b2, meta, order, out);
}

// Round 13
// 52.390 us; speedup vs baseline: 1.8547x; 1.0365x over previous
//
#include <hip/hip_runtime.h>

// MoE block: B=128,K=32 -> N=4096 tokens, D=1024, H=256, E=32, top-1 routing.
// out[tok] = relu(relu(x[tok] @ W1[e] + b1[e]) @ W2[e] + b2[e]), e = argmax(x@rw.T+rb)
// 4 launches (no tiny memset -- a 4B fill dispatch costs ~40us in-graph, R7/R10/R11):
// router, scan_scatter, expert_gemm<L1>, expert_gemm<L2>. Weights consumed in
// ORIGINAL fp32 [K][N] layout; transpose+bf16-cvt during LDS staging; depth-2
// register prefetch. L1 tiles are 32tok x 64col / 256thr (2x working blocks = 2/CU;
// R10 counters proved this loop is latency-bound at 1 block/CU: MfmaUtil 2.2%).
// L2 keeps the proven 32x128 / 512thr shape (~4 working blocks/CU).

#define N_TOK 4096
#define DDIM  1024
#define HDIM  256
#define NEXP  32
#define TPX   136          // max 32-token tiles per XCD class (<=132 worst case)

typedef __attribute__((ext_vector_type(8))) short bf16x8;   // 8 bf16 in 4 VGPRs
typedef __attribute__((ext_vector_type(4))) float f32x4;

__device__ __forceinline__ unsigned short f2bf(float f) {   // RNE f32->bf16
  union { float f; unsigned u; } v; v.f = f;
  unsigned r = v.u + 0x7FFFu + ((v.u >> 16) & 1u);
  return (unsigned short)(r >> 16);
}
__device__ __forceinline__ float bf2f(unsigned short h) {
  union { unsigned u; float f; } v; v.u = ((unsigned)h) << 16;
  return v.f;
}
// LDS tile addressing: row-major stride 72 shorts, kk bits 3-5 XORed with (row>>3)&7.
// b128 frag reads ~floor; b64 A-writes floor; b128 B-writes exact floor.
__device__ __forceinline__ int swz(int row, int kk) {
  return row * 72 + (kk ^ (((row >> 3) & 7) << 3));
}

// ---------------- K1: router (fp32-accurate logits via 4-term bf16 split MFMA) --------
// 512 thr = 8 waves per 16-token tile; wave w owns K window [w*128,+128).
__global__ __launch_bounds__(512) void router_kernel(
    const float* __restrict__ x, const float* __restrict__ rw,
    const float* __restrict__ rb, int* __restrict__ routed) {
  __shared__ float red[8][64][8];
  int b = blockIdx.x;
  int t = threadIdx.x, w = t >> 6, l = t & 63;
  int m = l & 15, kb = l >> 4;
  int tok = b * 16 + m;
  int kbase = w * 128;
  bf16x8 wh[2][4], wl[2][4];              // rw rows m, m+16; this thread's k-window
#pragma unroll
  for (int h = 0; h < 2; h++) {
    const float* wp = rw + (size_t)(m + h * 16) * DDIM + kbase + kb * 8;
#pragma unroll
    for (int q = 0; q < 4; q++) {
      float4 f0 = *(const float4*)(wp + q * 32);
      float4 f1 = *(const float4*)(wp + q * 32 + 4);
      float fv[8] = {f0.x, f0.y, f0.z, f0.w, f1.x, f1.y, f1.z, f1.w};
      bf16x8 hi, lo;
#pragma unroll
      for (int i = 0; i < 8; i++) {
        unsigned short hh = f2bf(fv[i]);
        hi[i] = (short)hh;
        lo[i] = (short)f2bf(fv[i] - bf2f(hh));
      }
      wh[h][q] = hi; wl[h][q] = lo;
    }
  }
  const float* xrow = x + (size_t)tok * DDIM + kbase + kb * 8;
  f32x4 acc0 = {0.f,0.f,0.f,0.f}, acc1 = {0.f,0.f,0.f,0.f};
#pragma unroll
  for (int q = 0; q < 4; q++) {
    float4 xa = *(const float4*)(xrow + q * 32);
    float4 xc = *(const float4*)(xrow + q * 32 + 4);
    float xv[8] = {xa.x, xa.y, xa.z, xa.w, xc.x, xc.y, xc.z, xc.w};
    bf16x8 xhi, xlo;
#pragma unroll
    for (int i = 0; i < 8; i++) {
      unsigned short hh = f2bf(xv[i]);
      xhi[i] = (short)hh;
      xlo[i] = (short)f2bf(xv[i] - bf2f(hh));
    }
    acc0 = __builtin_amdgcn_mfma_f32_16x16x32_bf16(xhi, wh[0][q], acc0, 0, 0, 0);
    acc0 = __builtin_amdgcn_mfma_f32_16x16x32_bf16(xlo, wh[0][q], acc0, 0, 0, 0);
    acc0 = __builtin_amdgcn_mfma_f32_16x16x32_bf16(xhi, wl[0][q], acc0, 0, 0, 0);
    acc0 = __builtin_amdgcn_mfma_f32_16x16x32_bf16(xlo, wl[0][q], acc0, 0, 0, 0);
    acc1 = __builtin_amdgcn_mfma_f32_16x16x32_bf16(xhi, wh[1][q], acc1, 0, 0, 0);
    acc1 = __builtin_amdgcn_mfma_f32_16x16x32_bf16(xlo, wh[1][q], acc1, 0, 0, 0);
    acc1 = __builtin_amdgcn_mfma_f32_16x16x32_bf16(xhi, wl[1][q], acc1, 0, 0, 0);
    acc1 = __builtin_amdgcn_mfma_f32_16x16x32_bf16(xlo, wl[1][q], acc1, 0, 0, 0);
  }
  *(f32x4*)&red[w][l][0] = acc0;
  *(f32x4*)&red[w][l][4] = acc1;
  __syncthreads();
  if (w == 0) {
    f32x4 s0 = {0.f,0.f,0.f,0.f}, s1 = {0.f,0.f,0.f,0.f};
#pragma unroll
    for (int ww = 0; ww < 8; ww++) {
      s0 += *(const f32x4*)&red[ww][l][0];
      s1 += *(const f32x4*)&red[ww][l][4];
    }
    float rb0 = rb[m], rb1 = rb[16 + m];
#pragma unroll
    for (int r = 0; r < 4; r++) {       // token row = kb*4+r
      float v0 = s0[r] + rb0;
      float v1 = s1[r] + rb1;
      float val = v0; int idx = m;
      if (v1 > v0) { val = v1; idx = 16 + m; }   // ties -> smaller e (np.argmax)
#pragma unroll
      for (int s = 1; s < 16; s <<= 1) {
        float ov = __shfl_xor(val, s);
        int oi = __shfl_xor(idx, s);
        if (ov > val || (ov == val && oi < idx)) { val = ov; idx = oi; }
      }
      if (m == 0) routed[b * 16 + kb * 4 + r] = idx;
    }
  }
}

// ---------------- K2: histogram + scan + XCD-pinned tile slots + scatter --------------
// meta[0..7] = tiles per XCD class; meta[8 + cls + 8*rank] = (e<<24)|(nrow<<16)|start.
// All tiles of expert e sit at consecutive ranks of class e&7 (L2 temporal locality).
__global__ __launch_bounds__(512) void scan_scatter_kernel(const int* __restrict__ routed,
    int* __restrict__ meta, int* __restrict__ order) {
  __shared__ int scnt[NEXP];
  __shared__ int scur[NEXP];
  int t = threadIdx.x;
  if (t < NEXP) scnt[t] = 0;
  __syncthreads();
  for (int n = t; n < N_TOK; n += 512) atomicAdd(&scnt[routed[n]], 1);
  __syncthreads();
  if (t < NEXP) {                           // lanes 0..31 of wave 0
    int c = scnt[t];
    int nt = (c + 31) >> 5;                 // 32-token tiles
    int ic = c;
#pragma unroll
    for (int s = 1; s < NEXP; s <<= 1) {
      int pc = __shfl_up(ic, s);
      if (t >= s) ic += pc;
    }
    int off = ic - c;
    scur[t] = off;
    int cls = t & 7, pos = t >> 3;          // XCD class, rank-in-class position
    int rank = 0;
#pragma unroll
    for (int j = 0; j < 4; j++) {
      int v = __shfl(nt, cls + j * 8);
      if (pos > j) rank += v;
    }
    for (int s2 = 0; s2 < nt; s2++) {
      int nr = c - s2 * 32; if (nr > 32) nr = 32;
      meta[8 + cls + 8 * (rank + s2)] = (t << 24) | (nr << 16) | (off + s2 * 32);
    }
    if (pos == 3) meta[cls] = rank + nt;    // per-class tile count
  }
  __syncthreads();
  for (int n = t; n < N_TOK; n += 512) {
    int e = routed[n];
    int p = atomicAdd(&scur[e], 1);         // intra-expert order arbitrary: out invariant
    order[p] = n;
  }
}

// ---------------- K3/K4: grouped GEMM with in-LDS transpose of fp32 weights ----------
// Tile 32 tok x COLS cols, THREADS = COLS*4 (4 or 8 waves, wave w owns 16 cols).
// Per 64-k chunk: stage A (gathered rows, fp32->bf16 for L1; NPASS passes of the
// proven 16-thr/row float4 pattern) and B (W[k][n] fp32 -> bf16 transposed, b128
// ds_write at exact bank floor) into swizzled LDS. Depth-2 register prefetch;
// vmcnt stays in flight across the barrier. 1-D grid, y-OUTERMOST in rank order.
template <int KDIM, int NTOT, int COLS, int THREADS, bool A_FP32, bool OUT_BF16>
__global__ __launch_bounds__(THREADS) void expert_gemm_kernel(
    const void* __restrict__ a_src, const float* __restrict__ wsrc,
    const float* __restrict__ bias, const int* __restrict__ meta,
    const int* __restrict__ order, void* __restrict__ outp) {
  constexpr int NCH = KDIM / 64;
  constexpr int NSLAB = NTOT / COLS;
  constexpr int NPASS = (32 * 16) / THREADS;  // A-staging passes: 512thr->1, 256thr->2
  __shared__ unsigned short AT[2][32 * 72];   //  9.2 KB
  __shared__ unsigned short BT[2][COLS * 72]; // 36.9 KB (128) / 18.4 KB (64)
  int bid = blockIdx.x, xcd = bid & 7, r = bid >> 3;
  int ntc = meta[xcd];
  if (r >= ntc * NSLAB) return;
  int y = r / ntc, rank = r - y * ntc;
  int info = meta[8 + xcd + 8 * rank];
  int e = info >> 24, nrow = (info >> 16) & 0xff, ts = info & 0xffff;
  int c0 = y * COLS;
  int t = threadIdx.x, w = t >> 6, l = t & 63, m = l & 15, kb = l >> 4;
  // staging roles: A = 32 rows x 64 kk (16 thr/row, float4/ushort4, NPASS passes);
  //                B = col bcn=t&(COLS-1), k-groups bkg=t/COLS and bkg+4 (8 k's each)
  int ak4 = (t & 15) * 4;
  int bcn = t & (COLS - 1), bkg = t / COLS;   // bkg in 0..3 for both shapes
  int atrp[NPASS];
  const float* aF[NPASS];
  const unsigned short* aH[NPASS];
#pragma unroll
  for (int pp = 0; pp < NPASS; pp++) {
    atrp[pp] = (t >> 4) + pp * (THREADS >> 4);
    int atok = order[ts + (atrp[pp] < nrow ? atrp[pp] : nrow - 1)];  // clamp: masked
    aF[pp] = (const float*)a_src + (size_t)atok * KDIM + ak4;
    aH[pp] = (const unsigned short*)a_src + (size_t)atok * KDIM + ak4;
  }
  const float* bS = wsrc + (size_t)e * KDIM * NTOT + c0 + bcn;

  float4 nAf[2][NPASS]; ushort4 nAh[2][NPASS];
  float nB[2][2][8];                          // all indices compile-time (full unroll)
  auto LOADC = [&](int c, int rbuf) {
#pragma unroll
    for (int pp = 0; pp < NPASS; pp++) {
      if constexpr (A_FP32) nAf[rbuf][pp] = *(const float4*)(aF[pp] + c * 64);
      else                  nAh[rbuf][pp] = *(const ushort4*)(aH[pp] + c * 64);
    }
#pragma unroll
    for (int u = 0; u < 2; u++)
#pragma unroll
      for (int j = 0; j < 8; j++)
        nB[rbuf][u][j] = bS[(size_t)(c * 64 + (bkg + 4 * u) * 8 + j) * NTOT];
  };

  f32x4 acc0 = {0.f,0.f,0.f,0.f}, acc1 = {0.f,0.f,0.f,0.f};
  LOADC(0, 0);
  LOADC(1, 1);
#pragma unroll
  for (int c = 0; c < NCH; c++) {
    const int p = c & 1;
#pragma unroll
    for (int pp = 0; pp < NPASS; pp++) {      // A writes b64: floor
      ushort4 av;
      if constexpr (A_FP32) {
        av.x = f2bf(nAf[p][pp].x); av.y = f2bf(nAf[p][pp].y);
        av.z = f2bf(nAf[p][pp].z); av.w = f2bf(nAf[p][pp].w);
      } else av = nAh[p][pp];
      *(ushort4*)&AT[p][swz(atrp[pp], ak4)] = av;
    }
#pragma unroll
    for (int u = 0; u < 2; u++) {             // B writes b128: exact bank floor
      bf16x8 pv;
#pragma unroll
      for (int j = 0; j < 8; j++) pv[j] = (short)f2bf(nB[p][u][j]);
      *(bf16x8*)&BT[p][swz(bcn, (bkg + 4 * u) * 8)] = pv;
    }
    if (c + 2 < NCH) LOADC(c + 2, p);         // WAR-safe: ds_writes read regs at issue
    asm volatile("s_waitcnt lgkmcnt(0)" ::: "memory");   // LDS writes visible
    __builtin_amdgcn_s_barrier();                        // vmcnt stays in flight
#pragma unroll
    for (int ks = 0; ks < 2; ks++) {
      int kk = ks * 32 + kb * 8;
      bf16x8 bfr = *(const bf16x8*)&BT[p][swz(w * 16 + m, kk)];
      bf16x8 a0  = *(const bf16x8*)&AT[p][swz(m, kk)];
      bf16x8 a1  = *(const bf16x8*)&AT[p][swz(16 + m, kk)];
      acc0 = __builtin_amdgcn_mfma_f32_16x16x32_bf16(a0, bfr, acc0, 0, 0, 0);
      acc1 = __builtin_amdgcn_mfma_f32_16x16x32_bf16(a1, bfr, acc1, 0, 0, 0);
    }
    // reads of buf p retire before next chunk's lgkmcnt(0)+barrier -> 1 barrier safe;
    // buf p is rewritten only at c+2, after that barrier.
  }
  int col = c0 + w * 16 + m;
  float bz = bias[e * NTOT + col];
#pragma unroll
  for (int r2 = 0; r2 < 4; r2++) {            // C/D: col=lane&15, row=kb*4+r (+16)
    int r0 = kb * 4 + r2;
    if (r0 < nrow) {
      int tok = order[ts + r0];
      float v = acc0[r2] + bz; v = v > 0.f ? v : 0.f;
      if constexpr (OUT_BF16)
        ((unsigned short*)outp)[(size_t)tok * NTOT + col] = f2bf(v);
      else
        ((float*)outp)[(size_t)tok * NTOT + col] = v;
    }
    int r1 = 16 + kb * 4 + r2;
    if (r1 < nrow) {
      int tok = order[ts + r1];
      float v = acc1[r2] + bz; v = v > 0.f ? v : 0.f;
      if constexpr (OUT_BF16)
        ((unsigned short*)outp)[(size_t)tok * NTOT + col] = f2bf(v);
      else
        ((float*)outp)[(size_t)tok * NTOT + col] = v;
    }
  }
}

// ---------------- launch ----------------

extern "C" void kernel_launch(void* const* d_in, const int* in_sizes, int n_in,
                              void* d_out, int out_size, void* d_ws, size_t ws_size,
                              hipStream_t stream) {
  const float* x  = (const float*)d_in[0];
  const float* rw = (const float*)d_in[1];
  const float* rb = (const float*)d_in[2];
  const float* w1 = (const float*)d_in[3];
  const float* b1 = (const float*)d_in[4];
  const float* w2 = (const float*)d_in[5];
  const float* b2 = (const float*)d_in[6];
  float* out = (float*)d_out;

  char* ws = (char*)d_ws;
  unsigned short* hb = (unsigned short*)(ws + 0);   // 2,097,152  h bf16 [N][H]
  int* routed = (int*)(ws + 2097152);               //    16,384
  int* order  = (int*)(ws + 2113536);               //    16,384
  int* meta   = (int*)(ws + 2129920);               //     4,608

  router_kernel<<<dim3(256), dim3(512), 0, stream>>>(x, rw, rb, routed);
  scan_scatter_kernel<<<dim3(1), dim3(512), 0, stream>>>(routed, meta, order);
  expert_gemm_kernel<DDIM, HDIM, 64, 256, true, true>
      <<<dim3(8 * TPX * (HDIM / 64)), dim3(256), 0, stream>>>(
      x, w1, b1, meta, order, hb);
  expert_gemm_kernel<HDIM, DDIM, 128, 512, false, false>
      <<<dim3(8 * TPX * (DDIM / 128)), dim3(512), 0, stream>>>(
      hb, w2, b2, meta, order, out);
}